// Round 1
// baseline (471.062 us; speedup 1.0000x reference)
//
#include <hip/hip_runtime.h>

// Problem constants
#define S_  2048
#define D_  1024
#define H_  16
#define DK_ 64
#define B_  4

typedef __attribute__((ext_vector_type(8))) short short8;
typedef __attribute__((ext_vector_type(4))) float f32x4;

__device__ __forceinline__ unsigned short f2bf(float f) {
  unsigned int u = __float_as_uint(f);
  u += 0x7fffu + ((u >> 16) & 1u);      // round-to-nearest-even
  return (unsigned short)(u >> 16);
}
__device__ __forceinline__ unsigned int pack2(float a, float b) {
  return (unsigned int)f2bf(a) | ((unsigned int)f2bf(b) << 16);
}

// 0.125 (1/sqrt(DK)) * log2(e)  -> use exp2 (native v_exp_f32)
#define SCL 0.18033688011112042f

// ---------------------------------------------------------------------------
// Fused attention: scores -> masked softmax -> write attn + column partials.
// grid = B*H * (S/64) = 2048 blocks, 256 threads (4 waves x 16 q-rows).
// Two passes over K: A computes row sums, B writes normalized attn.
// ---------------------------------------------------------------------------
__global__ __launch_bounds__(256) void attn_fused(
    const float* __restrict__ x, const int* __restrict__ sl32,
    float* __restrict__ attn, float* __restrict__ cpart)
{
  __shared__ __align__(16) unsigned short kbuf[128 * 64]; // 128 keys x 64 dims bf16, XOR-swizzled 16B chunks
  __shared__ float colbuf[4][128];

  const int blk = blockIdx.x;
  const int qt  = blk & 31;        // 32 q-tiles of 64 rows
  const int bh  = blk >> 5;        // 0..63
  const int b   = bh >> 4;
  const int h   = bh & 15;
  const int tid = threadIdx.x;
  const int wv  = tid >> 6;
  const int lane = tid & 63;
  const int lo  = lane & 15;       // col / row-within-tile lane index
  const int g   = lane >> 4;       // k-group (0..3)

  // seq_lens dtype auto-detect: values >= 1024, so int64 layout has sl32[1]==0
  const bool is64 = (sl32[1] == 0);
  const int seqlen = is64 ? sl32[2 * b] : sl32[b];

  const int qbase = qt * 64 + wv * 16;

  // Q fragments (A-frag): row = lo, k = g*8 + i + 32*s
  short8 aq[2];
  {
    const float* qp = x + ((size_t)b * S_ + (qbase + lo)) * D_ + h * DK_ + g * 8;
#pragma unroll
    for (int s = 0; s < 2; ++s) {
      const float4* p = (const float4*)(qp + s * 32);
      float4 v0 = p[0], v1 = p[1];
      short8 t;
      t[0] = (short)f2bf(v0.x); t[1] = (short)f2bf(v0.y);
      t[2] = (short)f2bf(v0.z); t[3] = (short)f2bf(v0.w);
      t[4] = (short)f2bf(v1.x); t[5] = (short)f2bf(v1.y);
      t[6] = (short)f2bf(v1.z); t[7] = (short)f2bf(v1.w);
      aq[s] = t;
    }
  }

  const int sr = tid >> 1, sh = tid & 1;   // staging: key row, 32-dim half
  auto stage = [&](int c0) {
    const float* kp = x + ((size_t)b * S_ + (c0 * 128 + sr)) * D_ + h * DK_ + sh * 32;
#pragma unroll
    for (int q = 0; q < 4; ++q) {
      float4 v0 = ((const float4*)kp)[2 * q];
      float4 v1 = ((const float4*)kp)[2 * q + 1];
      uint4 w;
      w.x = pack2(v0.x, v0.y);
      w.y = pack2(v0.z, v0.w);
      w.z = pack2(v1.x, v1.y);
      w.w = pack2(v1.z, v1.w);
      const int cs = (sh * 4 + q) ^ (sr & 7);
      *(uint4*)&kbuf[sr * 64 + cs * 8] = w;
    }
  };

  // One 16x16 score tile: key tile kt (0..7) of the staged 128-key chunk.
  auto qk_tile = [&](int kt) -> f32x4 {
    const int key = kt * 16 + lo;  // B-frag col
    f32x4 acc = {0.f, 0.f, 0.f, 0.f};
#pragma unroll
    for (int s = 0; s < 2; ++s) {
      const int cs = (s * 4 + g) ^ (key & 7);
      short8 bq = *(const short8*)&kbuf[key * 64 + cs * 8];
      acc = __builtin_amdgcn_mfma_f32_16x16x32_bf16(aq[s], bq, acc, 0, 0, 0);
    }
    return acc;
  };

  // ---------------- Pass A: row sums of exp ----------------
  float rsum[4] = {0.f, 0.f, 0.f, 0.f};
  for (int c0 = 0; c0 < 16; ++c0) {
    __syncthreads();
    stage(c0);
    __syncthreads();
    const int kbase = c0 * 128;
#pragma unroll
    for (int kt = 0; kt < 8; ++kt) {
      f32x4 acc = qk_tile(kt);
      const int kg = kbase + kt * 16 + lo;
      const bool valid = kg < seqlen;
#pragma unroll
      for (int r = 0; r < 4; ++r) {
        float e = valid ? exp2f(acc[r] * SCL) : 0.f;
        rsum[r] += e;
      }
    }
  }
  // reduce across the 16 col-lanes (same g group holds same rows)
#pragma unroll
  for (int r = 0; r < 4; ++r) {
    float v = rsum[r];
    v += __shfl_xor(v, 1);
    v += __shfl_xor(v, 2);
    v += __shfl_xor(v, 4);
    v += __shfl_xor(v, 8);
    rsum[r] = 1.0f / v;              // rsum now holds 1/l for rows g*4+r
  }

  // ---------------- Pass B: write attn + column partials ----------------
  float* arow = attn + (size_t)bh * S_ * S_;
  for (int c0 = 0; c0 < 16; ++c0) {
    __syncthreads();
    stage(c0);
    __syncthreads();
    const int kbase = c0 * 128;
#pragma unroll
    for (int kt = 0; kt < 8; ++kt) {
      f32x4 acc = qk_tile(kt);
      const int kg = kbase + kt * 16 + lo;
      const bool valid = kg < seqlen;
      float cv = 0.f;
#pragma unroll
      for (int r = 0; r < 4; ++r) {
        float e = valid ? exp2f(acc[r] * SCL) : 0.f;
        float a = e * rsum[r];
        arow[(size_t)(qbase + g * 4 + r) * S_ + kg] = a;
        cv += a;
      }
      cv += __shfl_xor(cv, 16);
      cv += __shfl_xor(cv, 32);
      if (lane < 16) colbuf[wv][kt * 16 + lo] = cv;
    }
    __syncthreads();
    if (tid < 128) {
      float s = colbuf[0][tid] + colbuf[1][tid] + colbuf[2][tid] + colbuf[3][tid];
      cpart[((size_t)bh * 32 + qt) * 2048 + kbase + tid] = s;
    }
  }
}

// c[bh][k] = sum over 32 q-tiles of cpart
__global__ __launch_bounds__(256) void creduce(const float* __restrict__ cpart,
                                               float* __restrict__ c) {
  const int i = blockIdx.x * 256 + threadIdx.x;   // 64*2048 total
  const int bh = i >> 11, k = i & 2047;
  float s = 0.f;
#pragma unroll 8
  for (int qt = 0; qt < 32; ++qt) s += cpart[((size_t)bh * 32 + qt) * 2048 + k];
  c[i] = s;
}

// csum[b][h*64+d] = sum_k c[bh][k] * x[b][k][h*64+d]
__global__ __launch_bounds__(256) void csum_k(const float* __restrict__ c,
                                              const float* __restrict__ x,
                                              float* __restrict__ csum) {
  __shared__ float part[4][64];
  const int bh = blockIdx.x, b = bh >> 4, h = bh & 15;
  const int seg = threadIdx.x >> 6, d = threadIdx.x & 63;
  const float* cb = c + bh * 2048;
  const float* xb = x + (size_t)b * S_ * D_ + h * DK_ + d;
  float acc = 0.f;
  for (int k = seg * 512; k < seg * 512 + 512; ++k)
    acc += cb[k] * xb[(size_t)k * D_];
  part[seg][d] = acc;
  __syncthreads();
  if (threadIdx.x < 64) {
    float s = part[0][d] + part[1][d] + part[2][d] + part[3][d];
    csum[b * D_ + h * DK_ + d] = s;
  }
}

// out0[b][d] = sum_e csum[b][e] * W[d][e] + S * bias[d]
__global__ __launch_bounds__(256) void proj_k(const float* __restrict__ csum,
                                              const float* __restrict__ W,
                                              const float* __restrict__ bias,
                                              float* __restrict__ out0) {
  const int idx = blockIdx.x * 4 + (threadIdx.x >> 6); // (b,d) pair per wave
  const int b = idx >> 10, d = idx & 1023;
  const int lane = threadIdx.x & 63;
  const float* wr = W + (size_t)d * D_;
  const float* cs = csum + b * D_;
  float acc = 0.f;
#pragma unroll
  for (int e = 0; e < 16; ++e) acc += cs[lane + e * 64] * wr[lane + e * 64];
  acc += __shfl_xor(acc, 32);
  acc += __shfl_xor(acc, 16);
  acc += __shfl_xor(acc, 8);
  acc += __shfl_xor(acc, 4);
  acc += __shfl_xor(acc, 2);
  acc += __shfl_xor(acc, 1);
  if (lane == 0) out0[idx] = acc + 2048.0f * bias[d];
}

extern "C" void kernel_launch(void* const* d_in, const int* in_sizes, int n_in,
                              void* d_out, int out_size, void* d_ws, size_t ws_size,
                              hipStream_t stream) {
  const float* x    = (const float*)d_in[0];
  const int*   sl   = (const int*)d_in[1];
  const float* W    = (const float*)d_in[2];
  const float* bias = (const float*)d_in[3];

  float* out0 = (float*)d_out;
  float* attn = out0 + B_ * D_;

  float* cpart = (float*)d_ws;                       // 64*32*2048 f32 = 16 MB
  float* c     = cpart + (size_t)64 * 32 * 2048;     // 64*2048 f32 = 512 KB
  float* csum  = c + 64 * 2048;                      // 4096 f32

  hipLaunchKernelGGL(attn_fused, dim3(2048), dim3(256), 0, stream, x, sl, attn, cpart);
  hipLaunchKernelGGL(creduce,    dim3(512),  dim3(256), 0, stream, cpart, c);
  hipLaunchKernelGGL(csum_k,     dim3(64),   dim3(256), 0, stream, c, x, csum);
  hipLaunchKernelGGL(proj_k,     dim3(1024), dim3(256), 0, stream, csum, W, bias, out0);
}